// Round 6
// baseline (119.615 us; speedup 1.0000x reference)
//
#include <hip/hip_runtime.h>

// ---------------------------------------------------------------------------
// Fused equivariant NLMP, MI355X.
// Main kernel: persistent work-stealing blocks; wave = output column j
// (uniform scalar-loaded fp16 weights with folded path constants), lane =
// edge. Per-edge data packed so each TP u-step is one ds_read_b128.
// CSR rank placement + streaming gather. Parallel 3-barrier scan.
// ---------------------------------------------------------------------------

#define EPB   64
#define BLOCK 512
#define NNP   10240
#define MAIN_GRID 1024

#define SQRT3_F      1.7320508075688772f
#define INV_SQRT3_F  0.5773502691896258f
#define INV_SQRT10_F 0.31622776601683794f
#define A1_4         0.044194173824159216f   // (1/sqrt(32)) * (1/4)
#define A2_4         0.0625f                 // (1/sqrt(16)) * (1/4)

typedef _Float16 f16;
typedef f16 f16x2 __attribute__((ext_vector_type(2)));
typedef f16 f16x4 __attribute__((ext_vector_type(4)));
typedef f16 f16x8 __attribute__((ext_vector_type(8)));

__global__ void zero_f32(float* __restrict__ p, int n) {
    int i = blockIdx.x * blockDim.x + threadIdx.x;
    if (i < n) p[i] = 0.0f;
}

// fused: zero counts + batch counter + convert weights to fp16 (u,j)-grouped
// layout with path constants folded in.
__global__ void prep(const float* __restrict__ W2, const float* __restrict__ W4,
                     f16* __restrict__ W2h, f16* __restrict__ W4h,
                     int* __restrict__ counts, int* __restrict__ ctr, int NN) {
    int gid = blockIdx.x * blockDim.x + threadIdx.x;
    if (gid < NN) counts[gid] = 0;
    if (gid == 0) *ctr = 0;
    if (gid >= NNP && gid < NNP + 8192) {
        int idx = gid - NNP;
        int q = idx >> 4, h = idx & 15;
        int u = (q & 127) >> 3, j = q & 7, p = q >> 7;
        float sc = (p == 1) ? (A1_4 * INV_SQRT3_F) : A1_4;
        W2h[(((u * 8 + j) * 4) + p) * 16 + h] = (f16)(W2[h * 512 + q] * sc);
    } else if (gid >= NNP + 8192 && gid < NNP + 8192 + 6144) {
        int idx = gid - NNP - 8192;
        int q = idx >> 4, h = idx & 15;
        int p = q >> 6, r = q & 63;
        int u = r >> 3, j = r & 7;
        float sc = (p == 1 || p == 3) ? (A2_4 * INV_SQRT3_F) : A2_4;
        W4h[(((u * 8 + j) * 6) + p) * 16 + h] = (f16)(W4[h * 384 + q] * sc);
    }
}

__global__ void hist_rank(const int* __restrict__ edst, int* __restrict__ counts,
                          int* __restrict__ rank, int E) {
    int e = blockIdx.x * blockDim.x + threadIdx.x;
    if (e < E) rank[e] = atomicAdd(&counts[edst[e]], 1);
}

// single-block scan, 10 elems/thread, two passes, 3 barriers
__global__ void scan_offsets(const int* __restrict__ counts, int* __restrict__ offsets, int nn) {
    __shared__ int wbase[16];
    const int tid = threadIdx.x, lane = tid & 63, w = tid >> 6;
    const int CH = (nn + 1023) >> 10;
    int s = 0;
    for (int k = 0; k < CH; ++k) {
        int i = tid * CH + k;
        if (i < nn) s += counts[i];
    }
    int sc = s;
    #pragma unroll
    for (int off = 1; off < 64; off <<= 1) {
        int t = __shfl_up(sc, off, 64);
        if (lane >= off) sc += t;
    }
    if (lane == 63) wbase[w] = sc;
    __syncthreads();
    if (tid < 16) {
        int v = wbase[tid];
        int p = v;
        #pragma unroll
        for (int off = 1; off < 16; off <<= 1) {
            int t = __shfl_up(p, off, 16);
            if (tid >= off) p += t;
        }
        wbase[tid] = p - v;   // exclusive wave base
    }
    __syncthreads();
    int excl = wbase[w] + sc - s;
    for (int k = 0; k < CH; ++k) {
        int i = tid * CH + k;
        if (i < nn) { offsets[i] = excl; excl += counts[i]; }
    }
}

__global__ void gather_out(const float* __restrict__ eout, const int* __restrict__ offsets,
                           const int* __restrict__ counts, float* __restrict__ out, int nn) {
    const int tid = threadIdx.x;
    const int n = blockIdx.x * 8 + (tid >> 5);
    const int t = tid & 31;
    if (n >= nn) return;
    const int beg = offsets[n];
    const int cnt = counts[n];
    float a0 = 0.0f, a1 = 0.0f;
    int k = 0;
    for (; k + 1 < cnt; k += 2) {
        a0 += eout[(size_t)(beg + k) * 32 + t];
        a1 += eout[(size_t)(beg + k + 1) * 32 + t];
    }
    if (k < cnt) a0 += eout[(size_t)(beg + k) * 32 + t];
    out[(size_t)n * 32 + t] = a0 + a1;
}

static __device__ __forceinline__ float dot16h(const f16x2* __restrict__ hh,
                                               const f16* __restrict__ w) {
    union U { f16x8 v; f16x2 p[4]; };
    U a, b;
    a.v = *(const f16x8*)(w);
    b.v = *(const f16x8*)(w + 8);
    float s = 0.0f;
#if __has_builtin(__builtin_amdgcn_fdot2)
    s = __builtin_amdgcn_fdot2(hh[0], a.p[0], s, false);
    s = __builtin_amdgcn_fdot2(hh[1], a.p[1], s, false);
    s = __builtin_amdgcn_fdot2(hh[2], a.p[2], s, false);
    s = __builtin_amdgcn_fdot2(hh[3], a.p[3], s, false);
    s = __builtin_amdgcn_fdot2(hh[4], b.p[0], s, false);
    s = __builtin_amdgcn_fdot2(hh[5], b.p[1], s, false);
    s = __builtin_amdgcn_fdot2(hh[6], b.p[2], s, false);
    s = __builtin_amdgcn_fdot2(hh[7], b.p[3], s, false);
#else
    #pragma unroll
    for (int i = 0; i < 4; ++i) {
        s += (float)hh[i][0]   * (float)a.p[i][0] + (float)hh[i][1]   * (float)a.p[i][1];
        s += (float)hh[i+4][0] * (float)b.p[i][0] + (float)hh[i+4][1] * (float)b.p[i][1];
    }
#endif
    return s;
}

static __device__ __forceinline__ float tanh_fast(float x) {
    x = fminf(fmaxf(x, -15.0f), 15.0f);
    float e = __expf(2.0f * x);
    return (e - 1.0f) * __builtin_amdgcn_rcpf(e + 1.0f);
}

// ATOMIC=0: write edge line to eout[pos[e]]; ATOMIC=1: atomicAdd into out[N][32]
template <int ATOMIC>
__global__ void __launch_bounds__(BLOCK, 8) eq_nlmp(
    const float* __restrict__ x,        // [N,32]
    const int*   __restrict__ esrc,     // [E]
    const int*   __restrict__ edst,     // [E]
    const float* __restrict__ evec,     // [E,3]
    const float* __restrict__ emb,      // [E,10]
    const float* __restrict__ nrm,      // [E]
    const float* __restrict__ W1,       // [10,16] fp32
    const float* __restrict__ W3,       // [10,16] fp32
    const f16*   __restrict__ W2h,
    const f16*   __restrict__ W4h,
    const int*   __restrict__ offsets,
    const int*   __restrict__ rank,
    float*       __restrict__ dst_buf,
    int*         __restrict__ ctr,
    int E, int nbatch)
{
    __shared__ float sXP  [EPB * 68];   // per edge u=0..15: [su,a0,a1,a2]; reused as sOUT
    __shared__ float sSTVT[EPB * 36];   // per edge u=0..7: [st,vt0,vt1,vt2]
    __shared__ float sEM  [EPB * 12];
    __shared__ float sSH  [EPB * 3];
    __shared__ f16   sH1  [EPB * 20];
    __shared__ f16   sH2  [EPB * 20];
    __shared__ float sW1t [16 * 12];    // transposed [hid][i]
    __shared__ float sW3t [16 * 12];
    __shared__ int   sPOS [EPB];
    __shared__ int   sDST [EPB];
    __shared__ float sNRM [EPB];
    __shared__ int   sBATCH;

    const int tid = threadIdx.x;
    const int e   = tid >> 3;
    const int q   = tid & 7;
    const int l   = tid & 63;
    const int js  = __builtin_amdgcn_readfirstlane(tid >> 6);

    if (tid < 160) {
        const int row = tid >> 4, hid = tid & 15;   // W1[row][hid]
        sW1t[hid * 12 + row] = W1[tid];
        sW3t[hid * 12 + row] = W3[tid];
    }
    // visibility of sW1t/sW3t covered by the first grab-barrier

    for (;;) {
        if (tid == 0) sBATCH = atomicAdd(ctr, 1);
        __syncthreads();
        const int b = sBATCH;
        if (b >= nbatch) break;

        const int ge0 = b * EPB;
        int ge = ge0 + e;
        const int nvalid = (E - ge0 < EPB) ? (E - ge0) : EPB;
        if (ge >= E) ge = E - 1;

        // ---- prelude: gather + repack per-edge data ----
        {
            const int src = esrc[ge];
            const int dst = edst[ge];
            const float4* xs4 = (const float4*)(x + (size_t)src * 32);
            const float4* xd4 = (const float4*)(x + (size_t)dst * 32);
            float4 a = xs4[q], bq = xd4[q];
            float av[4] = {a.x, a.y, a.z, a.w};
            float bv[4] = {bq.x, bq.y, bq.z, bq.w};
            #pragma unroll
            for (int m = 0; m < 4; ++m) {
                const int i = 4 * q + m;
                {
                    int pos;
                    if (i < 8) pos = 4 * i;
                    else { int r = i - 8; int u = (r * 2731) >> 13; pos = 4 * u + 1 + (r - 3 * u); }
                    sXP[e * 68 + pos] = av[m];
                }
                {
                    int pos;
                    if (i < 8) pos = 4 * (8 + i);
                    else { int r = i - 8; int u = (r * 2731) >> 13; pos = 4 * (8 + u) + 1 + (r - 3 * u); }
                    sXP[e * 68 + pos] = bv[m];
                }
            }
            if (q < 5) {
                float2 t = *(const float2*)(emb + (size_t)ge * 10 + 2 * q);
                sEM[e * 12 + 2 * q]     = t.x;
                sEM[e * 12 + 2 * q + 1] = t.y;
            }
            if (q == 0) {
                float vx = evec[(size_t)ge * 3 + 0];
                float vy = evec[(size_t)ge * 3 + 1];
                float vz = evec[(size_t)ge * 3 + 2];
                float rn = sqrtf(vx * vx + vy * vy + vz * vz);
                sSH[e * 3 + 0] = SQRT3_F * vx / rn;
                sSH[e * 3 + 1] = SQRT3_F * vy / rn;
                sSH[e * 3 + 2] = SQRT3_F * vz / rn;
            }
            if (q == 1) sNRM[e] = nrm[ge];
            if (q == 2) {
                if (ATOMIC) sDST[e] = dst;
                else        sPOS[e] = offsets[dst] + rank[ge];
            }
        }
        __syncthreads();

        // ---- MLP1 + MLP2: thread (e,q) computes hid = q, q+8 for both ----
        {
            float2 em0 = *(const float2*)&sEM[e * 12 + 0];
            float2 em1 = *(const float2*)&sEM[e * 12 + 2];
            float2 em2 = *(const float2*)&sEM[e * 12 + 4];
            float2 em3 = *(const float2*)&sEM[e * 12 + 6];
            float2 em4 = *(const float2*)&sEM[e * 12 + 8];
            #pragma unroll
            for (int t = 0; t < 2; ++t) {
                const int hid = q + 8 * t;
                {
                    const float4 wa = *(const float4*)&sW1t[hid * 12 + 0];
                    const float4 wb = *(const float4*)&sW1t[hid * 12 + 4];
                    const float2 wc = *(const float2*)&sW1t[hid * 12 + 8];
                    float acc = em0.x*wa.x + em0.y*wa.y + em1.x*wa.z + em1.y*wa.w
                              + em2.x*wb.x + em2.y*wb.y + em3.x*wb.z + em3.y*wb.w
                              + em4.x*wc.x + em4.y*wc.y;
                    sH1[e * 20 + hid] = (f16)fmaxf(acc * INV_SQRT10_F, 0.0f);
                }
                {
                    const float4 wa = *(const float4*)&sW3t[hid * 12 + 0];
                    const float4 wb = *(const float4*)&sW3t[hid * 12 + 4];
                    const float2 wc = *(const float2*)&sW3t[hid * 12 + 8];
                    float acc = em0.x*wa.x + em0.y*wa.y + em1.x*wa.z + em1.y*wa.w
                              + em2.x*wb.x + em2.y*wb.y + em3.x*wb.z + em3.y*wb.w
                              + em4.x*wc.x + em4.y*wc.y;
                    sH2[e * 20 + hid] = (f16)fmaxf(acc * INV_SQRT10_F, 0.0f);
                }
            }
        }
        __syncthreads();

        const float sh0 = sSH[l * 3 + 0], sh1 = sSH[l * 3 + 1], sh2 = sSH[l * 3 + 2];

        union HU { f16x4 q4[4]; f16x2 p[8]; };
        HU H;
        #pragma unroll
        for (int k = 0; k < 4; ++k) H.q4[k] = *(const f16x4*)&sH1[l * 20 + 4 * k];

        // ---- TP1 (a1/4 and 1/sqrt3 folded into W2h) ----
        float sts = 0.0f, svs = 0.0f, vt0 = 0.0f, vt1 = 0.0f, vt2 = 0.0f;
        #pragma unroll 2
        for (int u = 0; u < 16; ++u) {
            const float4 d = *(const float4*)&sXP[l * 68 + 4 * u];   // [su,a0,a1,a2]
            const float vd = d.y * sh0 + d.z * sh1 + d.w * sh2;
            const f16* wb = W2h + (size_t)((u * 8 + js) * 4) * 16;   // 128 B, wave-uniform
            const float wss = dot16h(H.p, wb);
            const float wvv = dot16h(H.p, wb + 16);
            const float wsv = dot16h(H.p, wb + 32);
            const float wvs = dot16h(H.p, wb + 48);
            sts += d.x * wss + vd * wvv;
            svs += d.x * wsv;
            vt0 += d.y * wvs;
            vt1 += d.z * wvs;
            vt2 += d.w * wvs;
        }
        {
            float4 stvt;
            stvt.x = sts;
            stvt.y = svs * sh0 + vt0;
            stvt.z = svs * sh1 + vt1;
            stvt.w = svs * sh2 + vt2;
            *(float4*)&sSTVT[l * 36 + 4 * js] = stvt;
        }
        __syncthreads();

        #pragma unroll
        for (int k = 0; k < 4; ++k) H.q4[k] = *(const f16x4*)&sH2[l * 20 + 4 * k];

        // ---- TP2 (a2/4 and 1/sqrt3 folded into W4h) ----
        float scal = 0.0f, gat = 0.0f, csv = 0.0f, vv0 = 0.0f, vv1 = 0.0f, vv2 = 0.0f;
        #pragma unroll 2
        for (int u = 0; u < 8; ++u) {
            const float4 d = *(const float4*)&sSTVT[l * 36 + 4 * u];  // [st,vt0,vt1,vt2]
            const float vd = d.y * sh0 + d.z * sh1 + d.w * sh2;
            const f16* wb = W4h + (size_t)((u * 8 + js) * 6) * 16;    // 192 B, wave-uniform
            const float wA  = dot16h(H.p, wb);
            const float wAv = dot16h(H.p, wb + 16);
            const float wB  = dot16h(H.p, wb + 32);
            const float wBv = dot16h(H.p, wb + 48);
            const float wC  = dot16h(H.p, wb + 64);
            const float wCv = dot16h(H.p, wb + 80);
            scal += d.x * wA + vd * wAv;
            gat  += d.x * wB + vd * wBv;
            csv  += d.x * wC;
            vv0  += d.y * wCv;
            vv1  += d.z * wCv;
            vv2  += d.w * wCv;
        }
        const float ve0 = csv * sh0 + vv0;
        const float ve1 = csv * sh1 + vv1;
        const float ve2 = csv * sh2 + vv2;

        const float nn = sNRM[l];
        const float ts = tanh_fast(scal) * nn;
        const float tg = tanh_fast(gat) * nn;

        if (ATOMIC) {
            if (l < nvalid) {
                float* ob = dst_buf + (size_t)sDST[l] * 32;
                atomicAdd(ob + js,             ts);
                atomicAdd(ob + 8 + 3 * js + 0, ve0 * tg);
                atomicAdd(ob + 8 + 3 * js + 1, ve1 * tg);
                atomicAdd(ob + 8 + 3 * js + 2, ve2 * tg);
            }
            __syncthreads();
        } else {
            float* sOUT = sXP;
            sOUT[l * 68 + js]             = ts;
            sOUT[l * 68 + 8 + 3 * js + 0] = ve0 * tg;
            sOUT[l * 68 + 8 + 3 * js + 1] = ve1 * tg;
            sOUT[l * 68 + 8 + 3 * js + 2] = ve2 * tg;
            __syncthreads();
            if (e < nvalid) {
                float4 v = *(const float4*)&sOUT[e * 68 + 4 * q];
                *(float4*)&dst_buf[(size_t)sPOS[e] * 32 + 4 * q] = v;
            }
            // next grab-barrier orders sOUT reads vs next prelude writes
        }
    }
}

extern "C" void kernel_launch(void* const* d_in, const int* in_sizes, int n_in,
                              void* d_out, int out_size, void* d_ws, size_t ws_size,
                              hipStream_t stream) {
    const float* x    = (const float*)d_in[0];
    const int*   esrc = (const int*)  d_in[1];
    const int*   edst = (const int*)  d_in[2];
    const float* evec = (const float*)d_in[3];
    const float* emb  = (const float*)d_in[4];
    const float* nrm  = (const float*)d_in[5];
    const float* W1   = (const float*)d_in[7];
    const float* W2   = (const float*)d_in[8];
    const float* W3   = (const float*)d_in[9];
    const float* W4   = (const float*)d_in[10];
    float* out = (float*)d_out;

    const int E  = in_sizes[1];
    const int NN = out_size / 32;
    const int nbatch = (E + EPB - 1) / EPB;

    size_t o_w2h   = 0;
    size_t o_w4h   = o_w2h + 512 * 16 * 2;
    size_t o_cnt   = o_w4h + 384 * 16 * 2;
    size_t o_off   = o_cnt + (size_t)NNP * 4;
    size_t o_rank  = o_off + (size_t)NNP * 4;
    size_t o_ctr   = (o_rank + (size_t)E * 4 + 255) & ~(size_t)255;
    size_t o_eout  = o_ctr + 256;
    size_t need    = o_eout + (size_t)E * 128;

    char* ws = (char*)d_ws;
    f16* W2h = (f16*)(ws + o_w2h);
    f16* W4h = (f16*)(ws + o_w4h);
    int*   counts  = (int*)  (ws + o_cnt);
    int*   offsets = (int*)  (ws + o_off);
    int*   rank    = (int*)  (ws + o_rank);
    int*   ctr     = (int*)  (ws + o_ctr);
    float* eout    = (float*)(ws + o_eout);

    const int prep_threads = NNP + 8192 + 6144;
    prep<<<(prep_threads + 255) / 256, 256, 0, stream>>>(W2, W4, W2h, W4h, counts, ctr, NN);

    const int grid = (nbatch < MAIN_GRID) ? nbatch : MAIN_GRID;

    if (NN <= NNP && ws_size >= need) {
        hist_rank<<<(E + 255) / 256, 256, 0, stream>>>(edst, counts, rank, E);
        scan_offsets<<<1, 1024, 0, stream>>>(counts, offsets, NN);
        eq_nlmp<0><<<grid, BLOCK, 0, stream>>>(x, esrc, edst, evec, emb, nrm,
                                               W1, W3, W2h, W4h, offsets, rank, eout,
                                               ctr, E, nbatch);
        gather_out<<<(NN + 7) / 8, 256, 0, stream>>>(eout, offsets, counts, out, NN);
    } else {
        zero_f32<<<(out_size + 255) / 256, 256, 0, stream>>>(out, out_size);
        eq_nlmp<1><<<grid, BLOCK, 0, stream>>>(x, esrc, edst, evec, emb, nrm,
                                               W1, W3, W2h, W4h, nullptr, nullptr, out,
                                               ctr, E, nbatch);
    }
}

// Round 7
// 96.614 us; speedup vs baseline: 1.2381x; 1.2381x over previous
//
#include <hip/hip_runtime.h>

// ---------------------------------------------------------------------------
// Fused equivariant NLMP, MI355X.
// Main kernel: one-shot blocks (1 batch of 64 edges each); wave = output
// column j (uniform scalar-loaded fp16 weights, path constants folded in),
// lane = edge. Per-edge data packed so each TP u-step is one ds_read_b128.
// CSR rank placement + streaming gather. 3-barrier parallel scan.
// ---------------------------------------------------------------------------

#define EPB   64
#define BLOCK 512
#define NNP   10240

#define SQRT3_F      1.7320508075688772f
#define INV_SQRT3_F  0.5773502691896258f
#define INV_SQRT10_F 0.31622776601683794f
#define A1_4         0.044194173824159216f   // (1/sqrt(32)) * (1/4)
#define A2_4         0.0625f                 // (1/sqrt(16)) * (1/4)

typedef _Float16 f16;
typedef f16 f16x2 __attribute__((ext_vector_type(2)));
typedef f16 f16x4 __attribute__((ext_vector_type(4)));
typedef f16 f16x8 __attribute__((ext_vector_type(8)));

__global__ void zero_f32(float* __restrict__ p, int n) {
    int i = blockIdx.x * blockDim.x + threadIdx.x;
    if (i < n) p[i] = 0.0f;
}

// fused: zero counts + convert weights to fp16 (u,j)-grouped layout with
// path constants folded in.
__global__ void prep(const float* __restrict__ W2, const float* __restrict__ W4,
                     f16* __restrict__ W2h, f16* __restrict__ W4h,
                     int* __restrict__ counts, int NN) {
    int gid = blockIdx.x * blockDim.x + threadIdx.x;
    if (gid < NN) counts[gid] = 0;
    if (gid >= NNP && gid < NNP + 8192) {
        int idx = gid - NNP;
        int q = idx >> 4, h = idx & 15;
        int u = (q & 127) >> 3, j = q & 7, p = q >> 7;
        float sc = (p == 1) ? (A1_4 * INV_SQRT3_F) : A1_4;
        W2h[(((u * 8 + j) * 4) + p) * 16 + h] = (f16)(W2[h * 512 + q] * sc);
    } else if (gid >= NNP + 8192 && gid < NNP + 8192 + 6144) {
        int idx = gid - NNP - 8192;
        int q = idx >> 4, h = idx & 15;
        int p = q >> 6, r = q & 63;
        int u = r >> 3, j = r & 7;
        float sc = (p == 1 || p == 3) ? (A2_4 * INV_SQRT3_F) : A2_4;
        W4h[(((u * 8 + j) * 6) + p) * 16 + h] = (f16)(W4[h * 384 + q] * sc);
    }
}

__global__ void hist_rank(const int* __restrict__ edst, int* __restrict__ counts,
                          int* __restrict__ rank, int E) {
    int e = blockIdx.x * blockDim.x + threadIdx.x;
    if (e < E) rank[e] = atomicAdd(&counts[edst[e]], 1);
}

// single-block scan, CH elems/thread, two passes, 3 barriers
__global__ void scan_offsets(const int* __restrict__ counts, int* __restrict__ offsets, int nn) {
    __shared__ int wbase[16];
    const int tid = threadIdx.x, lane = tid & 63, w = tid >> 6;
    const int CH = (nn + 1023) >> 10;
    int s = 0;
    for (int k = 0; k < CH; ++k) {
        int i = tid * CH + k;
        if (i < nn) s += counts[i];
    }
    int sc = s;
    #pragma unroll
    for (int off = 1; off < 64; off <<= 1) {
        int t = __shfl_up(sc, off, 64);
        if (lane >= off) sc += t;
    }
    if (lane == 63) wbase[w] = sc;
    __syncthreads();
    if (tid < 16) {
        int v = wbase[tid];
        int p = v;
        #pragma unroll
        for (int off = 1; off < 16; off <<= 1) {
            int t = __shfl_up(p, off, 16);
            if (tid >= off) p += t;
        }
        wbase[tid] = p - v;   // exclusive wave base
    }
    __syncthreads();
    int excl = wbase[w] + sc - s;
    for (int k = 0; k < CH; ++k) {
        int i = tid * CH + k;
        if (i < nn) { offsets[i] = excl; excl += counts[i]; }
    }
}

__global__ void gather_out(const float* __restrict__ eout, const int* __restrict__ offsets,
                           const int* __restrict__ counts, float* __restrict__ out, int nn) {
    const int tid = threadIdx.x;
    const int n = blockIdx.x * 8 + (tid >> 5);
    const int t = tid & 31;
    if (n >= nn) return;
    const int beg = offsets[n];
    const int cnt = counts[n];
    float a0 = 0.0f, a1 = 0.0f, a2 = 0.0f, a3 = 0.0f;
    int k = 0;
    for (; k + 3 < cnt; k += 4) {
        a0 += eout[(size_t)(beg + k) * 32 + t];
        a1 += eout[(size_t)(beg + k + 1) * 32 + t];
        a2 += eout[(size_t)(beg + k + 2) * 32 + t];
        a3 += eout[(size_t)(beg + k + 3) * 32 + t];
    }
    for (; k < cnt; ++k) a0 += eout[(size_t)(beg + k) * 32 + t];
    out[(size_t)n * 32 + t] = (a0 + a1) + (a2 + a3);
}

static __device__ __forceinline__ float dot16h(const f16x2* __restrict__ hh,
                                               const f16* __restrict__ w) {
    union U { f16x8 v; f16x2 p[4]; };
    U a, b;
    a.v = *(const f16x8*)(w);
    b.v = *(const f16x8*)(w + 8);
    float s = 0.0f;
#if __has_builtin(__builtin_amdgcn_fdot2)
    s = __builtin_amdgcn_fdot2(hh[0], a.p[0], s, false);
    s = __builtin_amdgcn_fdot2(hh[1], a.p[1], s, false);
    s = __builtin_amdgcn_fdot2(hh[2], a.p[2], s, false);
    s = __builtin_amdgcn_fdot2(hh[3], a.p[3], s, false);
    s = __builtin_amdgcn_fdot2(hh[4], b.p[0], s, false);
    s = __builtin_amdgcn_fdot2(hh[5], b.p[1], s, false);
    s = __builtin_amdgcn_fdot2(hh[6], b.p[2], s, false);
    s = __builtin_amdgcn_fdot2(hh[7], b.p[3], s, false);
#else
    #pragma unroll
    for (int i = 0; i < 4; ++i) {
        s += (float)hh[i][0]   * (float)a.p[i][0] + (float)hh[i][1]   * (float)a.p[i][1];
        s += (float)hh[i+4][0] * (float)b.p[i][0] + (float)hh[i+4][1] * (float)b.p[i][1];
    }
#endif
    return s;
}

static __device__ __forceinline__ float tanh_fast(float x) {
    x = fminf(fmaxf(x, -15.0f), 15.0f);
    float e = __expf(2.0f * x);
    return (e - 1.0f) * __builtin_amdgcn_rcpf(e + 1.0f);
}

// ATOMIC=0: write edge line to eout[pos[e]]; ATOMIC=1: atomicAdd into out[N][32]
template <int ATOMIC>
__global__ void __launch_bounds__(BLOCK, 8) eq_nlmp(
    const float* __restrict__ x,        // [N,32]
    const int*   __restrict__ esrc,     // [E]
    const int*   __restrict__ edst,     // [E]
    const float* __restrict__ evec,     // [E,3]
    const float* __restrict__ emb,      // [E,10]
    const float* __restrict__ nrm,      // [E]
    const float* __restrict__ W1,       // [10,16] fp32
    const float* __restrict__ W3,       // [10,16] fp32
    const f16*   __restrict__ W2h,
    const f16*   __restrict__ W4h,
    const int*   __restrict__ offsets,
    const int*   __restrict__ rank,
    float*       __restrict__ dst_buf,
    int E)
{
    __shared__ float sXP  [EPB * 68];   // per edge u=0..15: [su,a0,a1,a2]; reused as sOUT
    __shared__ float sSTVT[EPB * 36];   // per edge u=0..7: [st,vt0,vt1,vt2]
    __shared__ float sEM  [EPB * 12];
    __shared__ float sSH  [EPB * 3];
    __shared__ f16   sH1  [EPB * 20];
    __shared__ f16   sH2  [EPB * 20];
    __shared__ float sW1t [16 * 12];    // transposed [hid][i]
    __shared__ float sW3t [16 * 12];
    __shared__ int   sPOS [EPB];
    __shared__ int   sDST [EPB];
    __shared__ float sNRM [EPB];

    const int tid = threadIdx.x;
    const int e   = tid >> 3;
    const int q   = tid & 7;
    const int l   = tid & 63;
    const int js  = __builtin_amdgcn_readfirstlane(tid >> 6);

    const int ge0 = blockIdx.x * EPB;
    int ge = ge0 + e;
    const int nvalid = (E - ge0 < EPB) ? (E - ge0) : EPB;
    if (ge >= E) ge = E - 1;

    if (tid < 160) {
        const int row = tid >> 4, hid = tid & 15;   // W1[row][hid]
        sW1t[hid * 12 + row] = W1[tid];
        sW3t[hid * 12 + row] = W3[tid];
    }

    // ---- prelude: gather + repack per-edge data ----
    {
        const int src = esrc[ge];
        const int dst = edst[ge];
        const float4* xs4 = (const float4*)(x + (size_t)src * 32);
        const float4* xd4 = (const float4*)(x + (size_t)dst * 32);
        float4 a = xs4[q], bq = xd4[q];
        float av[4] = {a.x, a.y, a.z, a.w};
        float bv[4] = {bq.x, bq.y, bq.z, bq.w};
        #pragma unroll
        for (int m = 0; m < 4; ++m) {
            const int i = 4 * q + m;
            {
                int pos;
                if (i < 8) pos = 4 * i;
                else { int r = i - 8; int u = (r * 2731) >> 13; pos = 4 * u + 1 + (r - 3 * u); }
                sXP[e * 68 + pos] = av[m];
            }
            {
                int pos;
                if (i < 8) pos = 4 * (8 + i);
                else { int r = i - 8; int u = (r * 2731) >> 13; pos = 4 * (8 + u) + 1 + (r - 3 * u); }
                sXP[e * 68 + pos] = bv[m];
            }
        }
        if (q < 5) {
            float2 t = *(const float2*)(emb + (size_t)ge * 10 + 2 * q);
            sEM[e * 12 + 2 * q]     = t.x;
            sEM[e * 12 + 2 * q + 1] = t.y;
        }
        if (q == 0) {
            float vx = evec[(size_t)ge * 3 + 0];
            float vy = evec[(size_t)ge * 3 + 1];
            float vz = evec[(size_t)ge * 3 + 2];
            float rn = sqrtf(vx * vx + vy * vy + vz * vz);
            sSH[e * 3 + 0] = SQRT3_F * vx / rn;
            sSH[e * 3 + 1] = SQRT3_F * vy / rn;
            sSH[e * 3 + 2] = SQRT3_F * vz / rn;
        }
        if (q == 1) sNRM[e] = nrm[ge];
        if (q == 2) {
            if (ATOMIC) sDST[e] = dst;
            else        sPOS[e] = offsets[dst] + rank[ge];
        }
    }
    __syncthreads();

    // ---- MLP1 + MLP2: thread (e,q) computes hid = q, q+8 for both ----
    {
        float2 em0 = *(const float2*)&sEM[e * 12 + 0];
        float2 em1 = *(const float2*)&sEM[e * 12 + 2];
        float2 em2 = *(const float2*)&sEM[e * 12 + 4];
        float2 em3 = *(const float2*)&sEM[e * 12 + 6];
        float2 em4 = *(const float2*)&sEM[e * 12 + 8];
        #pragma unroll
        for (int t = 0; t < 2; ++t) {
            const int hid = q + 8 * t;
            {
                const float4 wa = *(const float4*)&sW1t[hid * 12 + 0];
                const float4 wb = *(const float4*)&sW1t[hid * 12 + 4];
                const float2 wc = *(const float2*)&sW1t[hid * 12 + 8];
                float acc = em0.x*wa.x + em0.y*wa.y + em1.x*wa.z + em1.y*wa.w
                          + em2.x*wb.x + em2.y*wb.y + em3.x*wb.z + em3.y*wb.w
                          + em4.x*wc.x + em4.y*wc.y;
                sH1[e * 20 + hid] = (f16)fmaxf(acc * INV_SQRT10_F, 0.0f);
            }
            {
                const float4 wa = *(const float4*)&sW3t[hid * 12 + 0];
                const float4 wb = *(const float4*)&sW3t[hid * 12 + 4];
                const float2 wc = *(const float2*)&sW3t[hid * 12 + 8];
                float acc = em0.x*wa.x + em0.y*wa.y + em1.x*wa.z + em1.y*wa.w
                          + em2.x*wb.x + em2.y*wb.y + em3.x*wb.z + em3.y*wb.w
                          + em4.x*wc.x + em4.y*wc.y;
                sH2[e * 20 + hid] = (f16)fmaxf(acc * INV_SQRT10_F, 0.0f);
            }
        }
    }
    __syncthreads();

    const float sh0 = sSH[l * 3 + 0], sh1 = sSH[l * 3 + 1], sh2 = sSH[l * 3 + 2];

    union HU { f16x4 q4[4]; f16x2 p[8]; };
    HU H;
    #pragma unroll
    for (int k = 0; k < 4; ++k) H.q4[k] = *(const f16x4*)&sH1[l * 20 + 4 * k];

    // ---- TP1 (a1/4 and 1/sqrt3 folded into W2h) ----
    float sts = 0.0f, svs = 0.0f, vt0 = 0.0f, vt1 = 0.0f, vt2 = 0.0f;
    #pragma unroll 2
    for (int u = 0; u < 16; ++u) {
        const float4 d = *(const float4*)&sXP[l * 68 + 4 * u];   // [su,a0,a1,a2]
        const float vd = d.y * sh0 + d.z * sh1 + d.w * sh2;
        const f16* wb = W2h + (size_t)((u * 8 + js) * 4) * 16;   // 128 B, wave-uniform
        const float wss = dot16h(H.p, wb);
        const float wvv = dot16h(H.p, wb + 16);
        const float wsv = dot16h(H.p, wb + 32);
        const float wvs = dot16h(H.p, wb + 48);
        sts += d.x * wss + vd * wvv;
        svs += d.x * wsv;
        vt0 += d.y * wvs;
        vt1 += d.z * wvs;
        vt2 += d.w * wvs;
    }
    {
        float4 stvt;
        stvt.x = sts;
        stvt.y = svs * sh0 + vt0;
        stvt.z = svs * sh1 + vt1;
        stvt.w = svs * sh2 + vt2;
        *(float4*)&sSTVT[l * 36 + 4 * js] = stvt;
    }
    __syncthreads();

    #pragma unroll
    for (int k = 0; k < 4; ++k) H.q4[k] = *(const f16x4*)&sH2[l * 20 + 4 * k];

    // ---- TP2 (a2/4 and 1/sqrt3 folded into W4h) ----
    float scal = 0.0f, gat = 0.0f, csv = 0.0f, vv0 = 0.0f, vv1 = 0.0f, vv2 = 0.0f;
    #pragma unroll 2
    for (int u = 0; u < 8; ++u) {
        const float4 d = *(const float4*)&sSTVT[l * 36 + 4 * u];  // [st,vt0,vt1,vt2]
        const float vd = d.y * sh0 + d.z * sh1 + d.w * sh2;
        const f16* wb = W4h + (size_t)((u * 8 + js) * 6) * 16;    // 192 B, wave-uniform
        const float wA  = dot16h(H.p, wb);
        const float wAv = dot16h(H.p, wb + 16);
        const float wB  = dot16h(H.p, wb + 32);
        const float wBv = dot16h(H.p, wb + 48);
        const float wC  = dot16h(H.p, wb + 64);
        const float wCv = dot16h(H.p, wb + 80);
        scal += d.x * wA + vd * wAv;
        gat  += d.x * wB + vd * wBv;
        csv  += d.x * wC;
        vv0  += d.y * wCv;
        vv1  += d.z * wCv;
        vv2  += d.w * wCv;
    }
    const float ve0 = csv * sh0 + vv0;
    const float ve1 = csv * sh1 + vv1;
    const float ve2 = csv * sh2 + vv2;

    const float nn = sNRM[l];
    const float ts = tanh_fast(scal) * nn;
    const float tg = tanh_fast(gat) * nn;

    if (ATOMIC) {
        if (l < nvalid) {
            float* ob = dst_buf + (size_t)sDST[l] * 32;
            atomicAdd(ob + js,             ts);
            atomicAdd(ob + 8 + 3 * js + 0, ve0 * tg);
            atomicAdd(ob + 8 + 3 * js + 1, ve1 * tg);
            atomicAdd(ob + 8 + 3 * js + 2, ve2 * tg);
        }
    } else {
        // stage outputs into sXP (all TP1 reads completed before STVT barrier)
        float* sOUT = sXP;
        sOUT[l * 68 + js]             = ts;
        sOUT[l * 68 + 8 + 3 * js + 0] = ve0 * tg;
        sOUT[l * 68 + 8 + 3 * js + 1] = ve1 * tg;
        sOUT[l * 68 + 8 + 3 * js + 2] = ve2 * tg;
        __syncthreads();
        if (e < nvalid) {
            float4 v = *(const float4*)&sOUT[e * 68 + 4 * q];
            *(float4*)&dst_buf[(size_t)sPOS[e] * 32 + 4 * q] = v;
        }
    }
}

extern "C" void kernel_launch(void* const* d_in, const int* in_sizes, int n_in,
                              void* d_out, int out_size, void* d_ws, size_t ws_size,
                              hipStream_t stream) {
    const float* x    = (const float*)d_in[0];
    const int*   esrc = (const int*)  d_in[1];
    const int*   edst = (const int*)  d_in[2];
    const float* evec = (const float*)d_in[3];
    const float* emb  = (const float*)d_in[4];
    const float* nrm  = (const float*)d_in[5];
    const float* W1   = (const float*)d_in[7];
    const float* W2   = (const float*)d_in[8];
    const float* W3   = (const float*)d_in[9];
    const float* W4   = (const float*)d_in[10];
    float* out = (float*)d_out;

    const int E  = in_sizes[1];
    const int NN = out_size / 32;
    const int nbatch = (E + EPB - 1) / EPB;

    size_t o_w2h   = 0;
    size_t o_w4h   = o_w2h + 512 * 16 * 2;
    size_t o_cnt   = o_w4h + 384 * 16 * 2;
    size_t o_off   = o_cnt + (size_t)NNP * 4;
    size_t o_rank  = o_off + (size_t)NNP * 4;
    size_t o_eout  = (o_rank + (size_t)E * 4 + 255) & ~(size_t)255;
    size_t need    = o_eout + (size_t)E * 128;

    char* ws = (char*)d_ws;
    f16* W2h = (f16*)(ws + o_w2h);
    f16* W4h = (f16*)(ws + o_w4h);
    int*   counts  = (int*)  (ws + o_cnt);
    int*   offsets = (int*)  (ws + o_off);
    int*   rank    = (int*)  (ws + o_rank);
    float* eout    = (float*)(ws + o_eout);

    const int prep_threads = NNP + 8192 + 6144;
    prep<<<(prep_threads + 255) / 256, 256, 0, stream>>>(W2, W4, W2h, W4h, counts, NN);

    if (NN <= NNP && ws_size >= need) {
        hist_rank<<<(E + 255) / 256, 256, 0, stream>>>(edst, counts, rank, E);
        scan_offsets<<<1, 1024, 0, stream>>>(counts, offsets, NN);
        eq_nlmp<0><<<nbatch, BLOCK, 0, stream>>>(x, esrc, edst, evec, emb, nrm,
                                                 W1, W3, W2h, W4h, offsets, rank, eout, E);
        gather_out<<<(NN + 7) / 8, 256, 0, stream>>>(eout, offsets, counts, out, NN);
    } else {
        zero_f32<<<(out_size + 255) / 256, 256, 0, stream>>>(out, out_size);
        eq_nlmp<1><<<nbatch, BLOCK, 0, stream>>>(x, esrc, edst, evec, emb, nrm,
                                                 W1, W3, W2h, W4h, nullptr, nullptr, out, E);
    }
}